// Round 5
// baseline (7858.509 us; speedup 1.0000x reference)
//
#include <hip/hip_runtime.h>
#include <hip/hip_bf16.h>
#include <math.h>

// AdaptiveViT forward. GEMMs: emulated-fp32 via PRE-SPLIT bf16 hi/lo planes and
// 3x MFMA 16x16x32 (ah*bh + al*bh + ah*bl). Split is done once per operand by
// producers (LN / attn / gelu epilogue / weight transpose), never in the K-loop.
// Weights are transposed+split per layer into a reused (N,K) plane slot.
// Residual stream / LN / softmax / attention in fp32.
//
// R1: gemm3 double-buffered LDS + XOR slot-swizzle.
// R2: attn 768x128 grid + defer-max online softmax + __expf.
// R3: attn 8-key-group ILP restructure; latent split into 3 parallel stages.
// R4: XCD-aware bijective block swizzle + BN=64 tile for N=768 GEMMs.
// R5: - attn split-K (flash-decode): 1536 blocks over (b,h,qhalf,khalf), each
//       computes partial (o,m,l); exact fp32 merge kernel. Occupancy 15->37%.
//       Partials alias Mh/Ml (idle until fc1).
//     - BN=64 gemm3: triple-buffered LDS + COUNTED s_waitcnt vmcnt(6) + raw
//       s_barrier (T4): the t+2 prefetch stays in flight across the barrier,
//       removing the per-K-step vmcnt(0) drain (was the fc2 stall: 96 K-steps
//       x ~full HBM latency each).

using bf16   = __hip_bfloat16;
using short8 = __attribute__((ext_vector_type(8))) short;
using f32x4  = __attribute__((ext_vector_type(4))) float;

#define GLD16(gptr, lptr)                                                            \
    __builtin_amdgcn_global_load_lds((const __attribute__((address_space(1))) void*)(gptr), \
                                     (__attribute__((address_space(3))) void*)(lptr), 16, 0, 0)

// counted-vmcnt barrier: wait own N-oldest-excluded loads, then join. The
// sched_barrier pins the wait (rule #18); barrier => all waves' waited loads
// are complete, so the buffer is readable while newer loads stay in flight.
#define WAIT_BARRIER(N)                                          \
    do {                                                         \
        asm volatile("s_waitcnt vmcnt(" #N ")" ::: "memory");    \
        __builtin_amdgcn_sched_barrier(0);                       \
        __builtin_amdgcn_s_barrier();                            \
        __builtin_amdgcn_sched_barrier(0);                       \
    } while (0)

// split f32 -> bf16 hi (RNE) + bf16 lo (truncated residual)
__device__ __forceinline__ void split2(float x, short& h, short& l)
{
    unsigned u  = __float_as_uint(x);
    unsigned hr = (u + 0x7fffu + ((u >> 16) & 1u)) & 0xffff0000u;
    h = (short)(hr >> 16);
    float res = x - __uint_as_float(hr);
    l = (short)(__float_as_uint(res) >> 16);
}

// ---------------------------------------------------------------------------
// W (K,N) f32 -> Wh/Wl (N,K) bf16 planes (transpose + split)
__global__ __launch_bounds__(256) void trans_split_kernel(const float* __restrict__ W,
                                                          short* __restrict__ Wh,
                                                          short* __restrict__ Wl,
                                                          int K, int N)
{
    __shared__ float tile[32][33];
    int n0 = blockIdx.x * 32, k0 = blockIdx.y * 32;
    int c = threadIdx.x & 31, r = threadIdx.x >> 5;
    #pragma unroll
    for (int i = 0; i < 32; i += 8)
        tile[r + i][c] = W[(size_t)(k0 + r + i) * N + n0 + c];
    __syncthreads();
    #pragma unroll
    for (int i = 0; i < 32; i += 8) {
        short h, l; split2(tile[c][r + i], h, l);
        size_t o = (size_t)(n0 + r + i) * K + k0 + c;
        Wh[o] = h; Wl[o] = l;
    }
}

// elementwise f32 -> hi/lo planes (for patch_w, already (N,K))
__global__ void split_kernel(const float* __restrict__ in, short* __restrict__ h,
                             short* __restrict__ l, int n)
{
    int i = blockIdx.x * 256 + threadIdx.x;
    if (i >= n) return;
    short hh, ll; split2(in[i], hh, ll);
    h[i] = hh; l[i] = ll;
}

// im2col + split: A[(b*196+p)][c*256+i*16+j] = x[b][c][py*16+i][px*16+j]
__global__ void im2col_split_kernel(const float* __restrict__ x,
                                    short* __restrict__ Ah, short* __restrict__ Al)
{
    int idx = blockIdx.x * 256 + threadIdx.x;
    if (idx >= 6272 * 768) return;
    int k = idx % 768;
    int row = idx / 768;
    int b = row / 196, p = row % 196;
    int py = p / 14, px = p % 14;
    int c = k >> 8, rem = k & 255;
    int i = rem >> 4, j = rem & 15;
    float v = x[(((size_t)b * 3 + c) * 224 + py * 16 + i) * 224 + px * 16 + j];
    short h, l; split2(v, h, l);
    Ah[idx] = h; Al[idx] = l;
}

// ---------------------------------------------------------------------------
// Emulated-fp32 GEMM on pre-split planes:
// C(MxN) = (Ah+Al)(MxK) @ (Bh+Bl)(NxK)^T + bias [+resid] [gelu] [split-out].
// 128xBN tile (BN = 128 or 64), BK=32, 4 waves, global_load_lds width-16
// staging, XOR-swizzled slots, contiguous ds_read_b128 fragments, 3 MFMAs per
// cell, XCD-aware block swizzle.
// BN=128: double-buffered LDS, one __syncthreads per K-step (proven R1 loop).
// BN=64 : triple-buffered LDS, counted vmcnt(6) + raw barrier (prefetch depth
//         2, never drains to 0 in the main loop).
template<int BN, bool GELU, bool RES, bool SPLITOUT>
__global__ __launch_bounds__(256) void gemm3_kernel(const short* __restrict__ Ah,
                                                    const short* __restrict__ Al,
                                                    const short* __restrict__ Bh,
                                                    const short* __restrict__ Bl,
                                                    const float* __restrict__ bias,
                                                    const float* __restrict__ resid,
                                                    float* __restrict__ Cf,
                                                    short* __restrict__ Ch,
                                                    short* __restrict__ Cl,
                                                    int M, int N, int K)
{
    constexpr int AL_OFF = 4096;             // shorts
    constexpr int BH_OFF = 8192;
    constexpr int BL_OFF = 8192 + BN * 32;
    constexpr int BUFSZ  = 8192 + BN * 64;   // shorts per buffer
    constexpr int NBUF   = (BN == 64) ? 3 : 2;
    constexpr int MI     = (BN == 128) ? 4 : 2;   // m-frags per wave
    __shared__ __align__(16) short sm[NBUF * BUFSZ];
    const int tid  = threadIdx.x;
    const int lane = tid & 63;
    const int w    = tid >> 6;
    const int wm   = (BN == 128) ? (w >> 1) : w;
    const int wn   = (BN == 128) ? (w & 1) : 0;

    // XCD-aware bijective swizzle (m204 formula).
    const int gx  = gridDim.x;
    const int nwg = gx * gridDim.y;
    const int wg  = blockIdx.y * gx + blockIdx.x;
    const int qq  = nwg >> 3, rr = nwg & 7;
    const int xcd = wg & 7, seq = wg >> 3;
    const int work = (xcd < rr ? xcd * (qq + 1) : rr * (qq + 1) + (xcd - rr) * qq) + seq;
    const int m0   = (work / gx) * 128;
    const int n0   = (work % gx) * BN;

    const int col  = lane & 15;
    const int quad = lane >> 4;
    const int srow = lane >> 2;        // staging row within 16-row chunk
    const int skc  = (((lane & 3) ^ ((lane >> 3) & 3)) * 8);
    const int rswz = (quad ^ ((col >> 1) & 3)) * 8;

    f32x4 acc[MI][4];
    #pragma unroll
    for (int i = 0; i < MI; ++i)
        #pragma unroll
        for (int j = 0; j < 4; ++j) acc[i][j] = (f32x4)0.f;

    const short* Ahb = Ah + (size_t)m0 * K;
    const short* Alb = Al + (size_t)m0 * K;
    const short* Bhb = Bh + (size_t)n0 * K;
    const short* Blb = Bl + (size_t)n0 * K;

    // 8 loads/wave/stage for BN=128, 6 for BN=64.
    auto stage = [&](short* dst, int t) {
        const int k0 = t << 5;
        #pragma unroll
        for (int i = 0; i < 2; ++i) {
            int r = w * 32 + i * 16;
            size_t go = (size_t)(r + srow) * K + k0 + skc;
            GLD16(Ahb + go, dst + r * 32);
            GLD16(Alb + go, dst + AL_OFF + r * 32);
            if (BN == 128) {
                GLD16(Bhb + go, dst + BH_OFF + r * 32);
                GLD16(Blb + go, dst + BL_OFF + r * 32);
            }
        }
        if (BN == 64) {
            int r = w * 16;
            size_t go = (size_t)(r + srow) * K + k0 + skc;
            GLD16(Bhb + go, dst + BH_OFF + r * 32);
            GLD16(Blb + go, dst + BL_OFF + r * 32);
        }
    };

    auto compute = [&](const short* cb) {
        short8 ah[MI], al[MI];
        #pragma unroll
        for (int mi = 0; mi < MI; ++mi) {
            int ao = (wm * (MI * 16) + mi * 16 + col) * 32 + rswz;
            ah[mi] = *(const short8*)(cb + ao);
            al[mi] = *(const short8*)(cb + AL_OFF + ao);
        }
        #pragma unroll
        for (int ni = 0; ni < 4; ++ni) {
            int bo = ((BN == 128 ? wn * 64 : 0) + ni * 16 + col) * 32 + rswz;
            short8 bh = *(const short8*)(cb + BH_OFF + bo);
            short8 bl = *(const short8*)(cb + BL_OFF + bo);
            #pragma unroll
            for (int mi = 0; mi < MI; ++mi) {
                acc[mi][ni] = __builtin_amdgcn_mfma_f32_16x16x32_bf16(ah[mi], bh, acc[mi][ni], 0, 0, 0);
                acc[mi][ni] = __builtin_amdgcn_mfma_f32_16x16x32_bf16(al[mi], bh, acc[mi][ni], 0, 0, 0);
                acc[mi][ni] = __builtin_amdgcn_mfma_f32_16x16x32_bf16(ah[mi], bl, acc[mi][ni], 0, 0, 0);
            }
        }
    };

    const int nk = K >> 5;
    if constexpr (BN == 64) {
        // triple buffer, prefetch depth 2, counted vmcnt (6 loads/wave/stage)
        short *p0 = sm, *p1 = sm + BUFSZ, *p2 = sm + 2 * BUFSZ;
        stage(p0, 0);
        stage(p1, 1);
        WAIT_BARRIER(6);                    // tile0 ready; tile1 in flight
        for (int t = 0; t + 2 < nk; ++t) {
            stage(p2, t + 2);               // 12 in flight
            compute(p0);
            WAIT_BARRIER(6);                // tile t+1 ready; t+2 in flight
            short* tmp = p0; p0 = p1; p1 = p2; p2 = tmp;
        }
        compute(p0);                        // tile nk-2
        WAIT_BARRIER(0);                    // tile nk-1 ready
        compute(p1);
    } else {
        // double buffer, one __syncthreads per K-step (R1 structure)
        stage(sm, 0);
        __syncthreads();
        int cur = 0;
        for (int t = 0; t < nk - 1; ++t) {
            stage(&sm[(cur ^ 1) * BUFSZ], t + 1);
            compute(&sm[cur * BUFSZ]);
            __syncthreads();
            cur ^= 1;
        }
        compute(&sm[cur * BUFSZ]);
    }

    #pragma unroll
    for (int mi = 0; mi < MI; ++mi) {
        #pragma unroll
        for (int ni = 0; ni < 4; ++ni) {
            int gcol = n0 + (BN == 128 ? wn * 64 : 0) + ni * 16 + col;
            float bv = bias[gcol];
            #pragma unroll
            for (int r = 0; r < 4; ++r) {
                int grow = m0 + wm * (MI * 16) + mi * 16 + quad * 4 + r;
                if (grow < M) {
                    float v = acc[mi][ni][r] + bv;
                    if (RES) v += resid[(size_t)grow * N + gcol];
                    if (GELU) v = 0.5f * v * (1.f + erff(v * 0.70710678118654752f));
                    size_t o = (size_t)grow * N + gcol;
                    if (SPLITOUT) { short h, l; split2(v, h, l); Ch[o] = h; Cl[o] = l; }
                    else          Cf[o] = v;
                }
            }
        }
    }
}

// ---------------------------------------------------------------------------
// LayerNorm over 768, fp32 in -> bf16 hi/lo planes. One wave per row.
__global__ __launch_bounds__(256) void ln_kernel(const float* __restrict__ x,
                                                 const float* __restrict__ g,
                                                 const float* __restrict__ bta,
                                                 short* __restrict__ outh,
                                                 short* __restrict__ outl, int M)
{
    int row = blockIdx.x * 4 + (threadIdx.x >> 6);
    int lane = threadIdx.x & 63;
    if (row >= M) return;
    const float* xr = x + (size_t)row * 768;
    float vals[12];
    float s = 0.f;
    #pragma unroll
    for (int i = 0; i < 12; ++i) { vals[i] = xr[lane + i * 64]; s += vals[i]; }
    #pragma unroll
    for (int off = 32; off; off >>= 1) s += __shfl_xor(s, off);
    float mean = s * (1.f / 768.f);
    float vs = 0.f;
    #pragma unroll
    for (int i = 0; i < 12; ++i) { float d = vals[i] - mean; vs += d * d; }
    #pragma unroll
    for (int off = 32; off; off >>= 1) vs += __shfl_xor(vs, off);
    float rstd = rsqrtf(vs * (1.f / 768.f) + 1e-5f);
    size_t rb = (size_t)row * 768;
    #pragma unroll
    for (int i = 0; i < 12; ++i) {
        int c = lane + i * 64;
        short h, l; split2((vals[i] - mean) * rstd * g[c] + bta[c], h, l);
        outh[rb + c] = h; outl[rb + c] = l;
    }
}

// ---------------------------------------------------------------------------
// Attention, split-K partial pass: one block per (b, head, q-half, k-half).
// 128 threads, one query row each; fp32; 8-key-group defer-max softmax.
// Writes UNNORMALIZED partial o plus (m, l) for the merge pass.
__global__ __launch_bounds__(128) void attn_part_kernel(const float* __restrict__ qkv,
                                                        float* __restrict__ Op,
                                                        float* __restrict__ Mp,
                                                        float* __restrict__ Lp, int S)
{
    __shared__ float Ks[64 * 64];
    __shared__ float Vs[64 * 64];
    int blk   = blockIdx.x;            // ((b*12 + h)*2 + qhalf)*2 + khalf
    int khalf = blk & 1, qhalf = (blk >> 1) & 1;
    int bh = blk >> 2;
    int b = bh / 12, h = bh % 12;
    int halfS = (S + 1) >> 1;          // 99
    int q0   = qhalf * halfS;
    int qcnt = min(halfS, S - q0);
    int k0   = khalf * halfS;
    int kcnt = min(halfS, S - k0);
    const float* base = qkv + (size_t)b * S * 2304;
    int tid = threadIdx.x;
    int r = q0 + tid;
    bool act = (tid < qcnt);
    float q[64];
    #pragma unroll
    for (int d = 0; d < 64; ++d) q[d] = 0.f;
    if (act) {
        const float4* qp = (const float4*)(base + (size_t)r * 2304 + h * 64);
        #pragma unroll
        for (int d4 = 0; d4 < 16; ++d4) {
            float4 t = qp[d4];
            q[4 * d4] = t.x; q[4 * d4 + 1] = t.y; q[4 * d4 + 2] = t.z; q[4 * d4 + 3] = t.w;
        }
    }
    float o[64];
    #pragma unroll
    for (int d = 0; d < 64; ++d) o[d] = 0.f;
    float m = -1e30f, l = 0.f;

    for (int jc = 0; jc < kcnt; jc += 64) {
        int cnt = min(64, kcnt - jc);
        __syncthreads();
        for (int idx = tid; idx < cnt * 16; idx += 128) {
            int j = idx >> 4, d4 = idx & 15;
            const float4* rp = (const float4*)(base + (size_t)(k0 + jc + j) * 2304 + h * 64) + d4;
            ((float4*)Ks)[j * 16 + d4] = rp[192];   // K = +768 floats
            ((float4*)Vs)[j * 16 + d4] = rp[384];   // V = +1536 floats
        }
        __syncthreads();
        if (act) {
            for (int j0 = 0; j0 < cnt; j0 += 8) {
                float sc[8];
                float pm = -1e30f;
                #pragma unroll
                for (int jj = 0; jj < 8; ++jj) {
                    int j = j0 + jj;
                    const float4* kr = (const float4*)&Ks[j * 64];
                    float s0 = 0.f, s1 = 0.f, s2 = 0.f, s3 = 0.f;
                    #pragma unroll
                    for (int d4 = 0; d4 < 16; ++d4) {
                        float4 kv = kr[d4];
                        s0 += q[4 * d4]     * kv.x;
                        s1 += q[4 * d4 + 1] * kv.y;
                        s2 += q[4 * d4 + 2] * kv.z;
                        s3 += q[4 * d4 + 3] * kv.w;
                    }
                    float sv = ((s0 + s1) + (s2 + s3)) * 0.125f;
                    sv = (j < cnt) ? sv : -1e30f;      // tail mask (exp -> 0)
                    sc[jj] = sv;
                    pm = fmaxf(pm, sv);
                }
                if (!__all(pm <= m + 8.f)) {           // defer-max, once per group
                    float mn = fmaxf(m, pm);
                    float alpha = __expf(m - mn);
                    l *= alpha;
                    #pragma unroll
                    for (int d = 0; d < 64; ++d) o[d] *= alpha;
                    m = mn;
                }
                #pragma unroll
                for (int jj = 0; jj < 8; ++jj) {
                    float p = __expf(sc[jj] - m);
                    l += p;
                    const float4* vr = (const float4*)&Vs[(j0 + jj) * 64];
                    #pragma unroll
                    for (int d4 = 0; d4 < 16; ++d4) {
                        float4 vv = vr[d4];
                        o[4 * d4]     += p * vv.x;
                        o[4 * d4 + 1] += p * vv.y;
                        o[4 * d4 + 2] += p * vv.z;
                        o[4 * d4 + 3] += p * vv.w;
                    }
                }
            }
        }
    }
    if (act) {
        size_t prow = (size_t)(khalf * 6400 + b * S + r);
        float* op = Op + prow * 768 + h * 64;
        #pragma unroll
        for (int d = 0; d < 64; ++d) op[d] = o[d];
        Mp[prow * 12 + h] = m;
        Lp[prow * 12 + h] = l;
    }
}

// Merge the two key-half partials: exact fp32 softmax combine, then bf16 split.
__global__ void attn_merge_kernel(const float* __restrict__ Op,
                                  const float* __restrict__ Mp,
                                  const float* __restrict__ Lp,
                                  short* __restrict__ Oh, short* __restrict__ Ol,
                                  int M)
{
    int idx = blockIdx.x * 256 + threadIdx.x;
    if (idx >= M * 768) return;
    int row = idx / 768;
    int h   = (idx % 768) >> 6;
    float m1 = Mp[(size_t)row * 12 + h],          m2 = Mp[(size_t)(6400 + row) * 12 + h];
    float l1 = Lp[(size_t)row * 12 + h],          l2 = Lp[(size_t)(6400 + row) * 12 + h];
    float mm = fmaxf(m1, m2);
    float a1 = __expf(m1 - mm), a2 = __expf(m2 - mm);
    float inv = 1.f / (l1 * a1 + l2 * a2);
    float v = (Op[(size_t)row * 768 + (idx % 768)] * a1 +
               Op[(size_t)(6400 + row) * 768 + (idx % 768)] * a2) * inv;
    short hh, ll; split2(v, hh, ll);
    Oh[idx] = hh; Ol[idx] = ll;
}

// ---------------------------------------------------------------------------
// Latent path, 3 parallel stages.
__global__ __launch_bounds__(256) void latent1_kernel(const float* __restrict__ pe_table,
                                                      const float* __restrict__ budget,
                                                      const float* __restrict__ w1,
                                                      const float* __restrict__ b1,
                                                      float* __restrict__ hout)
{
    int b = blockIdx.x, tid = threadIdx.x;
    __shared__ float pe[256];
    int idx = (int)rintf(budget[b] * 99.f);
    pe[tid] = pe_table[idx * 256 + tid];
    __syncthreads();
    int col = blockIdx.y * 256 + tid;
    float a = b1[col];
    for (int k = 0; k < 256; ++k) a += pe[k] * w1[k * 768 + col];
    hout[b * 768 + col] = 0.5f * a * (1.f + erff(a * 0.70710678118654752f));
}

// LN over 768 for the 32 latent rows, fp32 out. Wave per row.
__global__ __launch_bounds__(256) void ln32_kernel(const float* __restrict__ x,
                                                   const float* __restrict__ g,
                                                   const float* __restrict__ bta,
                                                   float* __restrict__ outp)
{
    int row = blockIdx.x * 4 + (threadIdx.x >> 6);
    int lane = threadIdx.x & 63;
    const float* xr = x + (size_t)row * 768;
    float vals[12];
    float s = 0.f;
    #pragma unroll
    for (int i = 0; i < 12; ++i) { vals[i] = xr[lane + i * 64]; s += vals[i]; }
    #pragma unroll
    for (int off = 32; off; off >>= 1) s += __shfl_xor(s, off);
    float mean = s * (1.f / 768.f);
    float vs = 0.f;
    #pragma unroll
    for (int i = 0; i < 12; ++i) { float d = vals[i] - mean; vs += d * d; }
    #pragma unroll
    for (int off = 32; off; off >>= 1) vs += __shfl_xor(vs, off);
    float rstd = rsqrtf(vs * (1.f / 768.f) + 1e-5f);
    size_t rb = (size_t)row * 768;
    #pragma unroll
    for (int i = 0; i < 12; ++i) {
        int c = lane + i * 64;
        outp[rb + c] = (vals[i] - mean) * rstd * g[c] + bta[c];
    }
}

__global__ __launch_bounds__(256) void latent2_kernel(const float* __restrict__ hn,
                                                      const float* __restrict__ w2,
                                                      const float* __restrict__ b2,
                                                      float* __restrict__ lat)
{
    int b = blockIdx.x, tid = threadIdx.x;
    __shared__ float hrow[768];
    for (int i = tid; i < 768; i += 256) hrow[i] = hn[b * 768 + i];
    __syncthreads();
    int col = blockIdx.y * 256 + tid;
    float a = b2[col];
    for (int k = 0; k < 768; ++k) a += hrow[k] * w2[k * 768 + col];
    lat[b * 768 + col] = a;
}

__global__ void assemble_kernel(const float* __restrict__ lat, const float* __restrict__ cls,
                                const float* __restrict__ P, const float* __restrict__ pos,
                                float* __restrict__ T)
{
    int idx = blockIdx.x * 256 + threadIdx.x;
    if (idx >= 32 * 198 * 768) return;
    int c = idx % 768;
    int row = idx / 768;
    int b = row / 198, t = row % 198;
    float v;
    if (t == 0)      v = lat[b * 768 + c];
    else if (t == 1) v = cls[c];
    else             v = P[((size_t)b * 196 + (t - 2)) * 768 + c];
    T[idx] = v + pos[t * 768 + c];
}

__global__ void sched_kernel(const float* __restrict__ T, const float* __restrict__ sw,
                             const float* __restrict__ sb, const float* __restrict__ budget,
                             int* __restrict__ active)
{
    int b = blockIdx.x, lane = threadIdx.x; // 64 threads
    const float* xr = T + (size_t)b * 198 * 768;
    float acc[6] = {0, 0, 0, 0, 0, 0};
    for (int k = lane; k < 768; k += 64) {
        float xv = xr[k];
        #pragma unroll
        for (int i = 0; i < 6; ++i) acc[i] += xv * sw[k * 6 + i];
    }
    #pragma unroll
    for (int i = 0; i < 6; ++i)
        #pragma unroll
        for (int off = 32; off; off >>= 1) acc[i] += __shfl_xor(acc[i], off);
    if (lane == 0) {
        float lg[6];
        #pragma unroll
        for (int i = 0; i < 6; ++i) lg[i] = acc[i] + sb[i];
        int k = (int)ceilf(budget[b] * 6.f);
        if (k < 1) k = 1;
        for (int i = 0; i < 6; ++i) {
            int rank = 0;
            for (int j = 0; j < 6; ++j)
                rank += (lg[j] > lg[i]) || (lg[j] == lg[i] && j < i);
            active[b * 6 + i] = (rank < k) ? 1 : 0;
        }
    }
}

__global__ void droplat_kernel(const float* __restrict__ T, float* __restrict__ T2)
{
    int idx = blockIdx.x * 256 + threadIdx.x;
    if (idx >= 32 * 197 * 768) return;
    int c = idx % 768;
    int row = idx / 768;
    int b = row / 197, t = row % 197;
    T2[idx] = T[((size_t)b * 198 + t + 1) * 768 + c];
}

__global__ void select_kernel(float* __restrict__ T2, const float* __restrict__ OUT,
                              const int* __restrict__ active, int layer)
{
    int idx = blockIdx.x * 256 + threadIdx.x;
    if (idx >= 32 * 197 * 768) return;
    int b = idx / (197 * 768);
    if (active[b * 6 + layer]) T2[idx] = OUT[idx];
}

__global__ __launch_bounds__(128) void head_kernel(const float* __restrict__ T2,
                                                   const float* __restrict__ g,
                                                   const float* __restrict__ bta,
                                                   const float* __restrict__ hw,
                                                   const float* __restrict__ hb,
                                                   float* __restrict__ out)
{
    int b = blockIdx.x, tid = threadIdx.x;
    __shared__ float hn[768];
    __shared__ float red[128];
    const float* xr = T2 + (size_t)b * 197 * 768;
    float v[6];
    float s = 0.f;
    #pragma unroll
    for (int i = 0; i < 6; ++i) { v[i] = xr[tid + i * 128]; s += v[i]; }
    red[tid] = s; __syncthreads();
    for (int o = 64; o > 0; o >>= 1) { if (tid < o) red[tid] += red[tid + o]; __syncthreads(); }
    float mean = red[0] * (1.f / 768.f);
    __syncthreads();
    float vs = 0.f;
    #pragma unroll
    for (int i = 0; i < 6; ++i) { float d = v[i] - mean; vs += d * d; }
    red[tid] = vs; __syncthreads();
    for (int o = 64; o > 0; o >>= 1) { if (tid < o) red[tid] += red[tid + o]; __syncthreads(); }
    float rstd = rsqrtf(red[0] * (1.f / 768.f) + 1e-5f);
    #pragma unroll
    for (int i = 0; i < 6; ++i) {
        int c = tid + i * 128;
        hn[c] = (v[i] - mean) * rstd * g[c] + bta[c];
    }
    __syncthreads();
    if (tid < 100) {
        float a = hb[tid];
        for (int k = 0; k < 768; ++k) a += hn[k] * hw[k * 100 + tid];
        out[b * 100 + tid] = a;
    }
}

// ---------------------------------------------------------------------------
extern "C" void kernel_launch(void* const* d_in, const int* in_sizes, int n_in,
                              void* d_out, int out_size, void* d_ws, size_t ws_size,
                              hipStream_t stream)
{
    const float* x        = (const float*)d_in[0];
    const float* budget   = (const float*)d_in[1];
    const float* pe_table = (const float*)d_in[2];
    const float* lat_w1   = (const float*)d_in[3];
    const float* lat_b1   = (const float*)d_in[4];
    const float* lat_ln_g = (const float*)d_in[5];
    const float* lat_ln_b = (const float*)d_in[6];
    const float* lat_w2   = (const float*)d_in[7];
    const float* lat_b2   = (const float*)d_in[8];
    const float* patch_w  = (const float*)d_in[9];
    const float* patch_b  = (const float*)d_in[10];
    const float* cls_tok  = (const float*)d_in[11];
    const float* pos_emb  = (const float*)d_in[12];
    const float* sched_w  = (const float*)d_in[13];
    const float* sched_b  = (const float*)d_in[14];
    const float* ln1_g    = (const float*)d_in[15];
    const float* ln1_b    = (const float*)d_in[16];
    const float* qkv_w    = (const float*)d_in[17];
    const float* qkv_b    = (const float*)d_in[18];
    const float* proj_w   = (const float*)d_in[19];
    const float* proj_b   = (const float*)d_in[20];
    const float* ln2_g    = (const float*)d_in[21];
    const float* ln2_b    = (const float*)d_in[22];
    const float* fc1_w    = (const float*)d_in[23];
    const float* fc1_b    = (const float*)d_in[24];
    const float* fc2_w    = (const float*)d_in[25];
    const float* fc2_b    = (const float*)d_in[26];
    const float* norm_g   = (const float*)d_in[27];
    const float* norm_b   = (const float*)d_in[28];
    const float* head_w   = (const float*)d_in[29];
    const float* head_b   = (const float*)d_in[30];
    float* out = (float*)d_out;
    (void)in_sizes; (void)n_in; (void)out_size; (void)ws_size;

    char* ws = (char*)d_ws;
    size_t off = 0;
    auto alloc = [&](size_t bytes) -> char* {
        char* p = ws + off;
        off = (off + bytes + 255) & ~(size_t)255;
        return p;
    };
    // per-layer weight plane slot (reused across layers)
    short* sQKVh = (short*)alloc(2304ull * 768 * 2);
    short* sQKVl = (short*)alloc(2304ull * 768 * 2);
    short* sPRJh = (short*)alloc(768ull * 768 * 2);
    short* sPRJl = (short*)alloc(768ull * 768 * 2);
    short* sFC1h = (short*)alloc(3072ull * 768 * 2);
    short* sFC1l = (short*)alloc(3072ull * 768 * 2);
    short* sFC2h = (short*)alloc(768ull * 3072 * 2);
    short* sFC2l = (short*)alloc(768ull * 3072 * 2);
    short* pwh   = (short*)alloc(768ull * 768 * 2);
    short* pwl   = (short*)alloc(768ull * 768 * 2);
    float* T     = (float*)alloc(6400ull * 768 * 4);   // padded to 6400 rows
    float* T2    = (float*)alloc(6400ull * 768 * 4);
    float* OUT   = (float*)alloc(6400ull * 768 * 4);
    short* Hh    = (short*)alloc(6400ull * 768 * 2);
    short* Hl    = (short*)alloc(6400ull * 768 * 2);
    float* QKV   = (float*)alloc(6336ull * 2304 * 4);
    short* Oh    = (short*)alloc(6400ull * 768 * 2);
    short* Ol    = (short*)alloc(6400ull * 768 * 2);
    short* Mh    = (short*)alloc(6400ull * 3072 * 2);
    short* Ml    = (short*)alloc(6400ull * 3072 * 2);
    float* lat   = (float*)alloc(32ull * 768 * 4);
    float* latH  = (float*)alloc(32ull * 768 * 4);
    float* latN  = (float*)alloc(32ull * 768 * 4);
    int*   act   = (int*)alloc(32 * 6 * 4);
    float* P     = QKV;          // alias: P consumed before first QKV write
    short* Aph   = Mh;           // alias: im2col planes consumed before first fc1
    short* Apl   = Ml;
    // attn split-K partials alias Mh/Ml (idle between fc2-read and fc1-write):
    // Opart needs 2*6400*768 f32 = 39.3 MB = sizeof(Mh) exactly.
    float* Opart = (float*)Mh;
    float* Mpart = (float*)Ml;
    float* Lpart = Mpart + 2 * 6400 * 12;

    // --- prologue: patch embed + latent + token assembly
    im2col_split_kernel<<<(6272 * 768 + 255) / 256, 256, 0, stream>>>(x, Aph, Apl);
    split_kernel<<<(768 * 768 + 255) / 256, 256, 0, stream>>>(patch_w, pwh, pwl, 768 * 768);
    latent1_kernel<<<dim3(32, 3), 256, 0, stream>>>(pe_table, budget, lat_w1, lat_b1, latH);
    ln32_kernel<<<8, 256, 0, stream>>>(latH, lat_ln_g, lat_ln_b, latN);
    latent2_kernel<<<dim3(32, 3), 256, 0, stream>>>(latN, lat_w2, lat_b2, lat);
    gemm3_kernel<64, false, false, false><<<dim3(12, 49), 256, 0, stream>>>(
        Aph, Apl, pwh, pwl, patch_b, nullptr, P, nullptr, nullptr, 6272, 768, 768);
    assemble_kernel<<<(32 * 198 * 768 + 255) / 256, 256, 0, stream>>>(lat, cls_tok, P, pos_emb, T);

    // --- 6 fixed blocks (S=198, M=6336)
    for (int l = 0; l < 6; ++l) {
        trans_split_kernel<<<dim3(72, 24), 256, 0, stream>>>(qkv_w + (size_t)l * 768 * 2304, sQKVh, sQKVl, 768, 2304);
        trans_split_kernel<<<dim3(24, 24), 256, 0, stream>>>(proj_w + (size_t)l * 768 * 768, sPRJh, sPRJl, 768, 768);
        trans_split_kernel<<<dim3(96, 24), 256, 0, stream>>>(fc1_w + (size_t)l * 768 * 3072, sFC1h, sFC1l, 768, 3072);
        trans_split_kernel<<<dim3(24, 96), 256, 0, stream>>>(fc2_w + (size_t)l * 3072 * 768, sFC2h, sFC2l, 3072, 768);

        ln_kernel<<<6336 / 4, 256, 0, stream>>>(T, ln1_g + l * 768, ln1_b + l * 768, Hh, Hl, 6336);
        gemm3_kernel<128, false, false, false><<<dim3(18, 50), 256, 0, stream>>>(
            Hh, Hl, sQKVh, sQKVl, qkv_b + l * 2304, nullptr, QKV, nullptr, nullptr, 6336, 2304, 768);
        attn_part_kernel<<<1536, 128, 0, stream>>>(QKV, Opart, Mpart, Lpart, 198);
        attn_merge_kernel<<<(6336 * 768 + 255) / 256, 256, 0, stream>>>(Opart, Mpart, Lpart, Oh, Ol, 6336);
        gemm3_kernel<64, false, true, false><<<dim3(12, 50), 256, 0, stream>>>(
            Oh, Ol, sPRJh, sPRJl, proj_b + l * 768, T, T, nullptr, nullptr, 6336, 768, 768);
        ln_kernel<<<6336 / 4, 256, 0, stream>>>(T, ln2_g + l * 768, ln2_b + l * 768, Hh, Hl, 6336);
        gemm3_kernel<128, true, false, true><<<dim3(24, 50), 256, 0, stream>>>(
            Hh, Hl, sFC1h, sFC1l, fc1_b + l * 3072, nullptr, nullptr, Mh, Ml, 6336, 3072, 768);
        gemm3_kernel<64, false, true, false><<<dim3(12, 50), 256, 0, stream>>>(
            Mh, Ml, sFC2h, sFC2l, fc2_b + l * 768, T, T, nullptr, nullptr, 6336, 768, 3072);
    }

    // --- scheduler + drop lat token
    sched_kernel<<<32, 64, 0, stream>>>(T, sched_w, sched_b, budget, act);
    droplat_kernel<<<(32 * 197 * 768 + 255) / 256, 256, 0, stream>>>(T, T2);

    // --- 6 adaptive blocks (S=197, M=6304): full compute then gated merge
    for (int i = 0; i < 6; ++i) {
        int l = 6 + i;
        trans_split_kernel<<<dim3(72, 24), 256, 0, stream>>>(qkv_w + (size_t)l * 768 * 2304, sQKVh, sQKVl, 768, 2304);
        trans_split_kernel<<<dim3(24, 24), 256, 0, stream>>>(proj_w + (size_t)l * 768 * 768, sPRJh, sPRJl, 768, 768);
        trans_split_kernel<<<dim3(96, 24), 256, 0, stream>>>(fc1_w + (size_t)l * 768 * 3072, sFC1h, sFC1l, 768, 3072);
        trans_split_kernel<<<dim3(24, 96), 256, 0, stream>>>(fc2_w + (size_t)l * 3072 * 768, sFC2h, sFC2l, 3072, 768);

        ln_kernel<<<6304 / 4, 256, 0, stream>>>(T2, ln1_g + l * 768, ln1_b + l * 768, Hh, Hl, 6304);
        gemm3_kernel<128, false, false, false><<<dim3(18, 50), 256, 0, stream>>>(
            Hh, Hl, sQKVh, sQKVl, qkv_b + l * 2304, nullptr, QKV, nullptr, nullptr, 6304, 2304, 768);
        attn_part_kernel<<<1536, 128, 0, stream>>>(QKV, Opart, Mpart, Lpart, 197);
        attn_merge_kernel<<<(6304 * 768 + 255) / 256, 256, 0, stream>>>(Opart, Mpart, Lpart, Oh, Ol, 6304);
        gemm3_kernel<64, false, true, false><<<dim3(12, 50), 256, 0, stream>>>(
            Oh, Ol, sPRJh, sPRJl, proj_b + l * 768, T2, OUT, nullptr, nullptr, 6304, 768, 768);
        ln_kernel<<<6304 / 4, 256, 0, stream>>>(OUT, ln2_g + l * 768, ln2_b + l * 768, Hh, Hl, 6304);
        gemm3_kernel<128, true, false, true><<<dim3(24, 50), 256, 0, stream>>>(
            Hh, Hl, sFC1h, sFC1l, fc1_b + l * 3072, nullptr, nullptr, Mh, Ml, 6304, 3072, 768);
        gemm3_kernel<64, false, true, false><<<dim3(12, 50), 256, 0, stream>>>(
            Mh, Ml, sFC2h, sFC2l, fc2_b + l * 768, OUT, OUT, nullptr, nullptr, 6304, 768, 3072);
        select_kernel<<<(32 * 197 * 768 + 255) / 256, 256, 0, stream>>>(T2, OUT, act, i);
    }

    // --- final LN + head
    head_kernel<<<32, 128, 0, stream>>>(T2, norm_g, norm_b, head_w, head_b, out);
}

// Round 6
// 7028.172 us; speedup vs baseline: 1.1181x; 1.1181x over previous
//
#include <hip/hip_runtime.h>
#include <hip/hip_bf16.h>
#include <math.h>

// AdaptiveViT forward. GEMMs: emulated-fp32 via PRE-SPLIT bf16 hi/lo planes and
// 3x MFMA 16x16x32 (ah*bh + al*bh + ah*bl). Split is done once per operand by
// producers (LN / attn / gelu epilogue / weight transpose), never in the K-loop.
// Weights are transposed+split per layer into a reused (N,K) plane slot.
// Residual stream / LN / softmax / attention in fp32.
//
// R1: gemm3 double-buffered LDS + XOR slot-swizzle.
// R2: attn 768-block grid + defer-max online softmax + __expf.
// R3: attn 8-key-group ILP restructure; latent split into 3 parallel stages.
// R4: XCD-aware bijective block swizzle + BN=64 tile for N=768 GEMMs.
// R5 (REVERTED): attn split-K doubled traffic with no occupancy gain (+660us);
//     BN=64 triple-buffer cut blocks/CU 3->2 (+170us).
// R6: attn d-split: thread = (query, d-half). q[32]+o[32] per thread (was
//     q[64]+o[64]=128 floats > VGPR budget -> AGPR/spill churn), half the LDS
//     bytes per thread (LDS stream was at the ~69TB/s ceiling), score = 32-dim
//     half-dot + one shfl_xor(1). 256 thr/block (198 active), 12 waves/CU.

using bf16   = __hip_bfloat16;
using short8 = __attribute__((ext_vector_type(8))) short;
using f32x4  = __attribute__((ext_vector_type(4))) float;

#define GLD16(gptr, lptr)                                                            \
    __builtin_amdgcn_global_load_lds((const __attribute__((address_space(1))) void*)(gptr), \
                                     (__attribute__((address_space(3))) void*)(lptr), 16, 0, 0)

// split f32 -> bf16 hi (RNE) + bf16 lo (truncated residual)
__device__ __forceinline__ void split2(float x, short& h, short& l)
{
    unsigned u  = __float_as_uint(x);
    unsigned hr = (u + 0x7fffu + ((u >> 16) & 1u)) & 0xffff0000u;
    h = (short)(hr >> 16);
    float res = x - __uint_as_float(hr);
    l = (short)(__float_as_uint(res) >> 16);
}

// ---------------------------------------------------------------------------
// W (K,N) f32 -> Wh/Wl (N,K) bf16 planes (transpose + split)
__global__ __launch_bounds__(256) void trans_split_kernel(const float* __restrict__ W,
                                                          short* __restrict__ Wh,
                                                          short* __restrict__ Wl,
                                                          int K, int N)
{
    __shared__ float tile[32][33];
    int n0 = blockIdx.x * 32, k0 = blockIdx.y * 32;
    int c = threadIdx.x & 31, r = threadIdx.x >> 5;
    #pragma unroll
    for (int i = 0; i < 32; i += 8)
        tile[r + i][c] = W[(size_t)(k0 + r + i) * N + n0 + c];
    __syncthreads();
    #pragma unroll
    for (int i = 0; i < 32; i += 8) {
        short h, l; split2(tile[c][r + i], h, l);
        size_t o = (size_t)(n0 + r + i) * K + k0 + c;
        Wh[o] = h; Wl[o] = l;
    }
}

// elementwise f32 -> hi/lo planes (for patch_w, already (N,K))
__global__ void split_kernel(const float* __restrict__ in, short* __restrict__ h,
                             short* __restrict__ l, int n)
{
    int i = blockIdx.x * 256 + threadIdx.x;
    if (i >= n) return;
    short hh, ll; split2(in[i], hh, ll);
    h[i] = hh; l[i] = ll;
}

// im2col + split: A[(b*196+p)][c*256+i*16+j] = x[b][c][py*16+i][px*16+j]
__global__ void im2col_split_kernel(const float* __restrict__ x,
                                    short* __restrict__ Ah, short* __restrict__ Al)
{
    int idx = blockIdx.x * 256 + threadIdx.x;
    if (idx >= 6272 * 768) return;
    int k = idx % 768;
    int row = idx / 768;
    int b = row / 196, p = row % 196;
    int py = p / 14, px = p % 14;
    int c = k >> 8, rem = k & 255;
    int i = rem >> 4, j = rem & 15;
    float v = x[(((size_t)b * 3 + c) * 224 + py * 16 + i) * 224 + px * 16 + j];
    short h, l; split2(v, h, l);
    Ah[idx] = h; Al[idx] = l;
}

// ---------------------------------------------------------------------------
// Emulated-fp32 GEMM on pre-split planes:
// C(MxN) = (Ah+Al)(MxK) @ (Bh+Bl)(NxK)^T + bias [+resid] [gelu] [split-out].
// 128xBN tile (BN = 128 or 64), BK=32, 4 waves, global_load_lds width-16
// staging, double-buffered LDS (one barrier per K-step), XOR-swizzled slots,
// contiguous ds_read_b128 fragments, 3 MFMAs per cell, XCD-aware block swizzle.
template<int BN, bool GELU, bool RES, bool SPLITOUT>
__global__ __launch_bounds__(256) void gemm3_kernel(const short* __restrict__ Ah,
                                                    const short* __restrict__ Al,
                                                    const short* __restrict__ Bh,
                                                    const short* __restrict__ Bl,
                                                    const float* __restrict__ bias,
                                                    const float* __restrict__ resid,
                                                    float* __restrict__ Cf,
                                                    short* __restrict__ Ch,
                                                    short* __restrict__ Cl,
                                                    int M, int N, int K)
{
    constexpr int AL_OFF = 4096;             // shorts
    constexpr int BH_OFF = 8192;
    constexpr int BL_OFF = 8192 + BN * 32;
    constexpr int BUFSZ  = 8192 + BN * 64;   // shorts per buffer
    constexpr int MI     = (BN == 128) ? 4 : 2;   // m-frags per wave
    __shared__ __align__(16) short sm[2 * BUFSZ];
    const int tid  = threadIdx.x;
    const int lane = tid & 63;
    const int w    = tid >> 6;
    const int wm   = (BN == 128) ? (w >> 1) : w;
    const int wn   = (BN == 128) ? (w & 1) : 0;

    // XCD-aware bijective swizzle (m204 formula).
    const int gx  = gridDim.x;
    const int nwg = gx * gridDim.y;
    const int wg  = blockIdx.y * gx + blockIdx.x;
    const int qq  = nwg >> 3, rr = nwg & 7;
    const int xcd = wg & 7, seq = wg >> 3;
    const int work = (xcd < rr ? xcd * (qq + 1) : rr * (qq + 1) + (xcd - rr) * qq) + seq;
    const int m0   = (work / gx) * 128;
    const int n0   = (work % gx) * BN;

    const int col  = lane & 15;
    const int quad = lane >> 4;
    const int srow = lane >> 2;        // staging row within 16-row chunk
    const int skc  = (((lane & 3) ^ ((lane >> 3) & 3)) * 8);
    const int rswz = (quad ^ ((col >> 1) & 3)) * 8;

    f32x4 acc[MI][4];
    #pragma unroll
    for (int i = 0; i < MI; ++i)
        #pragma unroll
        for (int j = 0; j < 4; ++j) acc[i][j] = (f32x4)0.f;

    const short* Ahb = Ah + (size_t)m0 * K;
    const short* Alb = Al + (size_t)m0 * K;
    const short* Bhb = Bh + (size_t)n0 * K;
    const short* Blb = Bl + (size_t)n0 * K;

    auto stage = [&](int buf, int t) {
        const int k0 = t << 5;
        short* dst = &sm[buf * BUFSZ];
        #pragma unroll
        for (int i = 0; i < 2; ++i) {
            int r = w * 32 + i * 16;
            size_t go = (size_t)(r + srow) * K + k0 + skc;
            GLD16(Ahb + go, dst + r * 32);
            GLD16(Alb + go, dst + AL_OFF + r * 32);
            if (BN == 128) {
                GLD16(Bhb + go, dst + BH_OFF + r * 32);
                GLD16(Blb + go, dst + BL_OFF + r * 32);
            }
        }
        if (BN == 64) {
            int r = w * 16;
            size_t go = (size_t)(r + srow) * K + k0 + skc;
            GLD16(Bhb + go, dst + BH_OFF + r * 32);
            GLD16(Blb + go, dst + BL_OFF + r * 32);
        }
    };

    auto compute = [&](int buf) {
        const short* cb = &sm[buf * BUFSZ];
        short8 ah[MI], al[MI];
        #pragma unroll
        for (int mi = 0; mi < MI; ++mi) {
            int ao = (wm * (MI * 16) + mi * 16 + col) * 32 + rswz;
            ah[mi] = *(const short8*)(cb + ao);
            al[mi] = *(const short8*)(cb + AL_OFF + ao);
        }
        #pragma unroll
        for (int ni = 0; ni < 4; ++ni) {
            int bo = ((BN == 128 ? wn * 64 : 0) + ni * 16 + col) * 32 + rswz;
            short8 bh = *(const short8*)(cb + BH_OFF + bo);
            short8 bl = *(const short8*)(cb + BL_OFF + bo);
            #pragma unroll
            for (int mi = 0; mi < MI; ++mi) {
                acc[mi][ni] = __builtin_amdgcn_mfma_f32_16x16x32_bf16(ah[mi], bh, acc[mi][ni], 0, 0, 0);
                acc[mi][ni] = __builtin_amdgcn_mfma_f32_16x16x32_bf16(al[mi], bh, acc[mi][ni], 0, 0, 0);
                acc[mi][ni] = __builtin_amdgcn_mfma_f32_16x16x32_bf16(ah[mi], bl, acc[mi][ni], 0, 0, 0);
            }
        }
    };

    const int nk = K >> 5;
    stage(0, 0);
    __syncthreads();
    int cur = 0;
    for (int t = 0; t < nk - 1; ++t) {
        stage(cur ^ 1, t + 1);      // prefetch next tile: latency hides under MFMAs;
        compute(cur);               // compiler's vmcnt(0) lands at the barrier below
        __syncthreads();
        cur ^= 1;
    }
    compute(cur);

    #pragma unroll
    for (int mi = 0; mi < MI; ++mi) {
        #pragma unroll
        for (int ni = 0; ni < 4; ++ni) {
            int gcol = n0 + (BN == 128 ? wn * 64 : 0) + ni * 16 + col;
            float bv = bias[gcol];
            #pragma unroll
            for (int r = 0; r < 4; ++r) {
                int grow = m0 + wm * (MI * 16) + mi * 16 + quad * 4 + r;
                if (grow < M) {
                    float v = acc[mi][ni][r] + bv;
                    if (RES) v += resid[(size_t)grow * N + gcol];
                    if (GELU) v = 0.5f * v * (1.f + erff(v * 0.70710678118654752f));
                    size_t o = (size_t)grow * N + gcol;
                    if (SPLITOUT) { short h, l; split2(v, h, l); Ch[o] = h; Cl[o] = l; }
                    else          Cf[o] = v;
                }
            }
        }
    }
}

// ---------------------------------------------------------------------------
// LayerNorm over 768, fp32 in -> bf16 hi/lo planes. One wave per row.
__global__ __launch_bounds__(256) void ln_kernel(const float* __restrict__ x,
                                                 const float* __restrict__ g,
                                                 const float* __restrict__ bta,
                                                 short* __restrict__ outh,
                                                 short* __restrict__ outl, int M)
{
    int row = blockIdx.x * 4 + (threadIdx.x >> 6);
    int lane = threadIdx.x & 63;
    if (row >= M) return;
    const float* xr = x + (size_t)row * 768;
    float vals[12];
    float s = 0.f;
    #pragma unroll
    for (int i = 0; i < 12; ++i) { vals[i] = xr[lane + i * 64]; s += vals[i]; }
    #pragma unroll
    for (int off = 32; off; off >>= 1) s += __shfl_xor(s, off);
    float mean = s * (1.f / 768.f);
    float vs = 0.f;
    #pragma unroll
    for (int i = 0; i < 12; ++i) { float d = vals[i] - mean; vs += d * d; }
    #pragma unroll
    for (int off = 32; off; off >>= 1) vs += __shfl_xor(vs, off);
    float rstd = rsqrtf(vs * (1.f / 768.f) + 1e-5f);
    size_t rb = (size_t)row * 768;
    #pragma unroll
    for (int i = 0; i < 12; ++i) {
        int c = lane + i * 64;
        short h, l; split2((vals[i] - mean) * rstd * g[c] + bta[c], h, l);
        outh[rb + c] = h; outl[rb + c] = l;
    }
}

// ---------------------------------------------------------------------------
// Attention, d-split: one block per (b, head, q-half); 256 threads; thread =
// (query, d-half). Each thread holds q[32]/o[32] (halves register pressure and
// LDS bytes/thread vs q[64]/o[64]). Score = 32-dim half-dot + shfl_xor(1);
// both pair lanes see identical s -> defer-max and l stay consistent.
// 8-key-group structure, __expf, tail keys masked to -1e30.
__global__ __launch_bounds__(256) void attn_kernel(const float* __restrict__ qkv,
                                                   short* __restrict__ Oh,
                                                   short* __restrict__ Ol, int S)
{
    __shared__ float Ks[64 * 64];
    __shared__ float Vs[64 * 64];
    int blk  = blockIdx.x;             // b*24 + h*2 + qhalf
    int bh   = blk >> 1, qhalf = blk & 1;
    int b = bh / 12, h = bh % 12;
    int halfS = (S + 1) >> 1;          // 99
    int q0   = qhalf * halfS;
    int qcnt = min(halfS, S - q0);
    const float* base = qkv + (size_t)b * S * 2304;
    int tid = threadIdx.x;
    int qi  = tid >> 1;                // query within chunk
    int dh  = tid & 1;                 // d-half: dims [dh*32, dh*32+32)
    int r   = q0 + qi;
    bool act = (qi < qcnt);
    float q[32];
    #pragma unroll
    for (int d = 0; d < 32; ++d) q[d] = 0.f;
    if (act) {
        const float4* qp = (const float4*)(base + (size_t)r * 2304 + h * 64 + dh * 32);
        #pragma unroll
        for (int d4 = 0; d4 < 8; ++d4) {
            float4 t = qp[d4];
            q[4 * d4] = t.x; q[4 * d4 + 1] = t.y; q[4 * d4 + 2] = t.z; q[4 * d4 + 3] = t.w;
        }
    }
    float o[32];
    #pragma unroll
    for (int d = 0; d < 32; ++d) o[d] = 0.f;
    float m = -1e30f, l = 0.f;

    for (int jc = 0; jc < S; jc += 64) {
        int cnt = min(64, S - jc);
        __syncthreads();
        for (int idx = tid; idx < cnt * 16; idx += 256) {
            int j = idx >> 4, d4 = idx & 15;
            const float4* rp = (const float4*)(base + (size_t)(jc + j) * 2304 + h * 64) + d4;
            ((float4*)Ks)[j * 16 + d4] = rp[192];   // K = +768 floats
            ((float4*)Vs)[j * 16 + d4] = rp[384];   // V = +1536 floats
        }
        __syncthreads();
        if (act) {
            for (int j0 = 0; j0 < cnt; j0 += 8) {
                float sc[8];
                float pm = -1e30f;
                #pragma unroll
                for (int jj = 0; jj < 8; ++jj) {
                    int j = j0 + jj;
                    const float4* kr = (const float4*)&Ks[j * 64 + dh * 32];
                    float s0 = 0.f, s1 = 0.f, s2 = 0.f, s3 = 0.f;
                    #pragma unroll
                    for (int d4 = 0; d4 < 8; ++d4) {
                        float4 kv = kr[d4];
                        s0 += q[4 * d4]     * kv.x;
                        s1 += q[4 * d4 + 1] * kv.y;
                        s2 += q[4 * d4 + 2] * kv.z;
                        s3 += q[4 * d4 + 3] * kv.w;
                    }
                    float sh = (s0 + s1) + (s2 + s3);
                    float sv = (sh + __shfl_xor(sh, 1)) * 0.125f;  // full dot, both lanes
                    sv = (j < cnt) ? sv : -1e30f;                  // tail mask (exp -> 0)
                    sc[jj] = sv;
                    pm = fmaxf(pm, sv);
                }
                // defer-max: one check per 8-key group, BEFORE any exp of the
                // group is taken -> p <= e^8 always.
                if (!__all(pm <= m + 8.f)) {
                    float mn = fmaxf(m, pm);
                    float alpha = __expf(m - mn);
                    l *= alpha;
                    #pragma unroll
                    for (int d = 0; d < 32; ++d) o[d] *= alpha;
                    m = mn;
                }
                #pragma unroll
                for (int jj = 0; jj < 8; ++jj) {
                    float p = __expf(sc[jj] - m);
                    l += p;
                    const float4* vr = (const float4*)&Vs[(j0 + jj) * 64 + dh * 32];
                    #pragma unroll
                    for (int d4 = 0; d4 < 8; ++d4) {
                        float4 vv = vr[d4];
                        o[4 * d4]     += p * vv.x;
                        o[4 * d4 + 1] += p * vv.y;
                        o[4 * d4 + 2] += p * vv.z;
                        o[4 * d4 + 3] += p * vv.w;
                    }
                }
            }
        }
    }
    if (act) {
        float inv = 1.f / l;
        size_t rb = (size_t)(b * S + r) * 768 + h * 64 + dh * 32;
        #pragma unroll
        for (int d = 0; d < 32; ++d) {
            short hh, ll; split2(o[d] * inv, hh, ll);
            Oh[rb + d] = hh; Ol[rb + d] = ll;
        }
    }
}

// ---------------------------------------------------------------------------
// Latent path, 3 parallel stages.
__global__ __launch_bounds__(256) void latent1_kernel(const float* __restrict__ pe_table,
                                                      const float* __restrict__ budget,
                                                      const float* __restrict__ w1,
                                                      const float* __restrict__ b1,
                                                      float* __restrict__ hout)
{
    int b = blockIdx.x, tid = threadIdx.x;
    __shared__ float pe[256];
    int idx = (int)rintf(budget[b] * 99.f);
    pe[tid] = pe_table[idx * 256 + tid];
    __syncthreads();
    int col = blockIdx.y * 256 + tid;
    float a = b1[col];
    for (int k = 0; k < 256; ++k) a += pe[k] * w1[k * 768 + col];
    hout[b * 768 + col] = 0.5f * a * (1.f + erff(a * 0.70710678118654752f));
}

// LN over 768 for the 32 latent rows, fp32 out. Wave per row.
__global__ __launch_bounds__(256) void ln32_kernel(const float* __restrict__ x,
                                                   const float* __restrict__ g,
                                                   const float* __restrict__ bta,
                                                   float* __restrict__ outp)
{
    int row = blockIdx.x * 4 + (threadIdx.x >> 6);
    int lane = threadIdx.x & 63;
    const float* xr = x + (size_t)row * 768;
    float vals[12];
    float s = 0.f;
    #pragma unroll
    for (int i = 0; i < 12; ++i) { vals[i] = xr[lane + i * 64]; s += vals[i]; }
    #pragma unroll
    for (int off = 32; off; off >>= 1) s += __shfl_xor(s, off);
    float mean = s * (1.f / 768.f);
    float vs = 0.f;
    #pragma unroll
    for (int i = 0; i < 12; ++i) { float d = vals[i] - mean; vs += d * d; }
    #pragma unroll
    for (int off = 32; off; off >>= 1) vs += __shfl_xor(vs, off);
    float rstd = rsqrtf(vs * (1.f / 768.f) + 1e-5f);
    size_t rb = (size_t)row * 768;
    #pragma unroll
    for (int i = 0; i < 12; ++i) {
        int c = lane + i * 64;
        outp[rb + c] = (vals[i] - mean) * rstd * g[c] + bta[c];
    }
}

__global__ __launch_bounds__(256) void latent2_kernel(const float* __restrict__ hn,
                                                      const float* __restrict__ w2,
                                                      const float* __restrict__ b2,
                                                      float* __restrict__ lat)
{
    int b = blockIdx.x, tid = threadIdx.x;
    __shared__ float hrow[768];
    for (int i = tid; i < 768; i += 256) hrow[i] = hn[b * 768 + i];
    __syncthreads();
    int col = blockIdx.y * 256 + tid;
    float a = b2[col];
    for (int k = 0; k < 768; ++k) a += hrow[k] * w2[k * 768 + col];
    lat[b * 768 + col] = a;
}

__global__ void assemble_kernel(const float* __restrict__ lat, const float* __restrict__ cls,
                                const float* __restrict__ P, const float* __restrict__ pos,
                                float* __restrict__ T)
{
    int idx = blockIdx.x * 256 + threadIdx.x;
    if (idx >= 32 * 198 * 768) return;
    int c = idx % 768;
    int row = idx / 768;
    int b = row / 198, t = row % 198;
    float v;
    if (t == 0)      v = lat[b * 768 + c];
    else if (t == 1) v = cls[c];
    else             v = P[((size_t)b * 196 + (t - 2)) * 768 + c];
    T[idx] = v + pos[t * 768 + c];
}

__global__ void sched_kernel(const float* __restrict__ T, const float* __restrict__ sw,
                             const float* __restrict__ sb, const float* __restrict__ budget,
                             int* __restrict__ active)
{
    int b = blockIdx.x, lane = threadIdx.x; // 64 threads
    const float* xr = T + (size_t)b * 198 * 768;
    float acc[6] = {0, 0, 0, 0, 0, 0};
    for (int k = lane; k < 768; k += 64) {
        float xv = xr[k];
        #pragma unroll
        for (int i = 0; i < 6; ++i) acc[i] += xv * sw[k * 6 + i];
    }
    #pragma unroll
    for (int i = 0; i < 6; ++i)
        #pragma unroll
        for (int off = 32; off; off >>= 1) acc[i] += __shfl_xor(acc[i], off);
    if (lane == 0) {
        float lg[6];
        #pragma unroll
        for (int i = 0; i < 6; ++i) lg[i] = acc[i] + sb[i];
        int k = (int)ceilf(budget[b] * 6.f);
        if (k < 1) k = 1;
        for (int i = 0; i < 6; ++i) {
            int rank = 0;
            for (int j = 0; j < 6; ++j)
                rank += (lg[j] > lg[i]) || (lg[j] == lg[i] && j < i);
            active[b * 6 + i] = (rank < k) ? 1 : 0;
        }
    }
}

__global__ void droplat_kernel(const float* __restrict__ T, float* __restrict__ T2)
{
    int idx = blockIdx.x * 256 + threadIdx.x;
    if (idx >= 32 * 197 * 768) return;
    int c = idx % 768;
    int row = idx / 768;
    int b = row / 197, t = row % 197;
    T2[idx] = T[((size_t)b * 198 + t + 1) * 768 + c];
}

__global__ void select_kernel(float* __restrict__ T2, const float* __restrict__ OUT,
                              const int* __restrict__ active, int layer)
{
    int idx = blockIdx.x * 256 + threadIdx.x;
    if (idx >= 32 * 197 * 768) return;
    int b = idx / (197 * 768);
    if (active[b * 6 + layer]) T2[idx] = OUT[idx];
}

__global__ __launch_bounds__(128) void head_kernel(const float* __restrict__ T2,
                                                   const float* __restrict__ g,
                                                   const float* __restrict__ bta,
                                                   const float* __restrict__ hw,
                                                   const float* __restrict__ hb,
                                                   float* __restrict__ out)
{
    int b = blockIdx.x, tid = threadIdx.x;
    __shared__ float hn[768];
    __shared__ float red[128];
    const float* xr = T2 + (size_t)b * 197 * 768;
    float v[6];
    float s = 0.f;
    #pragma unroll
    for (int i = 0; i < 6; ++i) { v[i] = xr[tid + i * 128]; s += v[i]; }
    red[tid] = s; __syncthreads();
    for (int o = 64; o > 0; o >>= 1) { if (tid < o) red[tid] += red[tid + o]; __syncthreads(); }
    float mean = red[0] * (1.f / 768.f);
    __syncthreads();
    float vs = 0.f;
    #pragma unroll
    for (int i = 0; i < 6; ++i) { float d = v[i] - mean; vs += d * d; }
    red[tid] = vs; __syncthreads();
    for (int o = 64; o > 0; o >>= 1) { if (tid < o) red[tid] += red[tid + o]; __syncthreads(); }
    float rstd = rsqrtf(red[0] * (1.f / 768.f) + 1e-5f);
    #pragma unroll
    for (int i = 0; i < 6; ++i) {
        int c = tid + i * 128;
        hn[c] = (v[i] - mean) * rstd * g[c] + bta[c];
    }
    __syncthreads();
    if (tid < 100) {
        float a = hb[tid];
        for (int k = 0; k < 768; ++k) a += hn[k] * hw[k * 100 + tid];
        out[b * 100 + tid] = a;
    }
}

// ---------------------------------------------------------------------------
extern "C" void kernel_launch(void* const* d_in, const int* in_sizes, int n_in,
                              void* d_out, int out_size, void* d_ws, size_t ws_size,
                              hipStream_t stream)
{
    const float* x        = (const float*)d_in[0];
    const float* budget   = (const float*)d_in[1];
    const float* pe_table = (const float*)d_in[2];
    const float* lat_w1   = (const float*)d_in[3];
    const float* lat_b1   = (const float*)d_in[4];
    const float* lat_ln_g = (const float*)d_in[5];
    const float* lat_ln_b = (const float*)d_in[6];
    const float* lat_w2   = (const float*)d_in[7];
    const float* lat_b2   = (const float*)d_in[8];
    const float* patch_w  = (const float*)d_in[9];
    const float* patch_b  = (const float*)d_in[10];
    const float* cls_tok  = (const float*)d_in[11];
    const float* pos_emb  = (const float*)d_in[12];
    const float* sched_w  = (const float*)d_in[13];
    const float* sched_b  = (const float*)d_in[14];
    const float* ln1_g    = (const float*)d_in[15];
    const float* ln1_b    = (const float*)d_in[16];
    const float* qkv_w    = (const float*)d_in[17];
    const float* qkv_b    = (const float*)d_in[18];
    const float* proj_w   = (const float*)d_in[19];
    const float* proj_b   = (const float*)d_in[20];
    const float* ln2_g    = (const float*)d_in[21];
    const float* ln2_b    = (const float*)d_in[22];
    const float* fc1_w    = (const float*)d_in[23];
    const float* fc1_b    = (const float*)d_in[24];
    const float* fc2_w    = (const float*)d_in[25];
    const float* fc2_b    = (const float*)d_in[26];
    const float* norm_g   = (const float*)d_in[27];
    const float* norm_b   = (const float*)d_in[28];
    const float* head_w   = (const float*)d_in[29];
    const float* head_b   = (const float*)d_in[30];
    float* out = (float*)d_out;
    (void)in_sizes; (void)n_in; (void)out_size; (void)ws_size;

    char* ws = (char*)d_ws;
    size_t off = 0;
    auto alloc = [&](size_t bytes) -> char* {
        char* p = ws + off;
        off = (off + bytes + 255) & ~(size_t)255;
        return p;
    };
    // per-layer weight plane slot (reused across layers)
    short* sQKVh = (short*)alloc(2304ull * 768 * 2);
    short* sQKVl = (short*)alloc(2304ull * 768 * 2);
    short* sPRJh = (short*)alloc(768ull * 768 * 2);
    short* sPRJl = (short*)alloc(768ull * 768 * 2);
    short* sFC1h = (short*)alloc(3072ull * 768 * 2);
    short* sFC1l = (short*)alloc(3072ull * 768 * 2);
    short* sFC2h = (short*)alloc(768ull * 3072 * 2);
    short* sFC2l = (short*)alloc(768ull * 3072 * 2);
    short* pwh   = (short*)alloc(768ull * 768 * 2);
    short* pwl   = (short*)alloc(768ull * 768 * 2);
    float* T     = (float*)alloc(6400ull * 768 * 4);   // padded to 6400 rows
    float* T2    = (float*)alloc(6400ull * 768 * 4);
    float* OUT   = (float*)alloc(6400ull * 768 * 4);
    short* Hh    = (short*)alloc(6400ull * 768 * 2);
    short* Hl    = (short*)alloc(6400ull * 768 * 2);
    float* QKV   = (float*)alloc(6336ull * 2304 * 4);
    short* Oh    = (short*)alloc(6400ull * 768 * 2);
    short* Ol    = (short*)alloc(6400ull * 768 * 2);
    short* Mh    = (short*)alloc(6400ull * 3072 * 2);
    short* Ml    = (short*)alloc(6400ull * 3072 * 2);
    float* lat   = (float*)alloc(32ull * 768 * 4);
    float* latH  = (float*)alloc(32ull * 768 * 4);
    float* latN  = (float*)alloc(32ull * 768 * 4);
    int*   act   = (int*)alloc(32 * 6 * 4);
    float* P     = QKV;          // alias: P consumed before first QKV write
    short* Aph   = Mh;           // alias: im2col planes consumed before first fc1
    short* Apl   = Ml;

    // --- prologue: patch embed + latent + token assembly
    im2col_split_kernel<<<(6272 * 768 + 255) / 256, 256, 0, stream>>>(x, Aph, Apl);
    split_kernel<<<(768 * 768 + 255) / 256, 256, 0, stream>>>(patch_w, pwh, pwl, 768 * 768);
    latent1_kernel<<<dim3(32, 3), 256, 0, stream>>>(pe_table, budget, lat_w1, lat_b1, latH);
    ln32_kernel<<<8, 256, 0, stream>>>(latH, lat_ln_g, lat_ln_b, latN);
    latent2_kernel<<<dim3(32, 3), 256, 0, stream>>>(latN, lat_w2, lat_b2, lat);
    gemm3_kernel<64, false, false, false><<<dim3(12, 49), 256, 0, stream>>>(
        Aph, Apl, pwh, pwl, patch_b, nullptr, P, nullptr, nullptr, 6272, 768, 768);
    assemble_kernel<<<(32 * 198 * 768 + 255) / 256, 256, 0, stream>>>(lat, cls_tok, P, pos_emb, T);

    // --- 6 fixed blocks (S=198, M=6336)
    for (int l = 0; l < 6; ++l) {
        trans_split_kernel<<<dim3(72, 24), 256, 0, stream>>>(qkv_w + (size_t)l * 768 * 2304, sQKVh, sQKVl, 768, 2304);
        trans_split_kernel<<<dim3(24, 24), 256, 0, stream>>>(proj_w + (size_t)l * 768 * 768, sPRJh, sPRJl, 768, 768);
        trans_split_kernel<<<dim3(96, 24), 256, 0, stream>>>(fc1_w + (size_t)l * 768 * 3072, sFC1h, sFC1l, 768, 3072);
        trans_split_kernel<<<dim3(24, 96), 256, 0, stream>>>(fc2_w + (size_t)l * 3072 * 768, sFC2h, sFC2l, 3072, 768);

        ln_kernel<<<6336 / 4, 256, 0, stream>>>(T, ln1_g + l * 768, ln1_b + l * 768, Hh, Hl, 6336);
        gemm3_kernel<128, false, false, false><<<dim3(18, 50), 256, 0, stream>>>(
            Hh, Hl, sQKVh, sQKVl, qkv_b + l * 2304, nullptr, QKV, nullptr, nullptr, 6336, 2304, 768);
        attn_kernel<<<768, 256, 0, stream>>>(QKV, Oh, Ol, 198);
        gemm3_kernel<64, false, true, false><<<dim3(12, 50), 256, 0, stream>>>(
            Oh, Ol, sPRJh, sPRJl, proj_b + l * 768, T, T, nullptr, nullptr, 6336, 768, 768);
        ln_kernel<<<6336 / 4, 256, 0, stream>>>(T, ln2_g + l * 768, ln2_b + l * 768, Hh, Hl, 6336);
        gemm3_kernel<128, true, false, true><<<dim3(24, 50), 256, 0, stream>>>(
            Hh, Hl, sFC1h, sFC1l, fc1_b + l * 3072, nullptr, nullptr, Mh, Ml, 6336, 3072, 768);
        gemm3_kernel<64, false, true, false><<<dim3(12, 50), 256, 0, stream>>>(
            Mh, Ml, sFC2h, sFC2l, fc2_b + l * 768, T, T, nullptr, nullptr, 6336, 768, 3072);
    }

    // --- scheduler + drop lat token
    sched_kernel<<<32, 64, 0, stream>>>(T, sched_w, sched_b, budget, act);
    droplat_kernel<<<(32 * 197 * 768 + 255) / 256, 256, 0, stream>>>(T, T2);

    // --- 6 adaptive blocks (S=197, M=6304): full compute then gated merge
    for (int i = 0; i < 6; ++i) {
        int l = 6 + i;
        trans_split_kernel<<<dim3(72, 24), 256, 0, stream>>>(qkv_w + (size_t)l * 768 * 2304, sQKVh, sQKVl, 768, 2304);
        trans_split_kernel<<<dim3(24, 24), 256, 0, stream>>>(proj_w + (size_t)l * 768 * 768, sPRJh, sPRJl, 768, 768);
        trans_split_kernel<<<dim3(96, 24), 256, 0, stream>>>(fc1_w + (size_t)l * 768 * 3072, sFC1h, sFC1l, 768, 3072);
        trans_split_kernel<<<dim3(24, 96), 256, 0, stream>>>(fc2_w + (size_t)l * 3072 * 768, sFC2h, sFC2l, 3072, 768);

        ln_kernel<<<6304 / 4, 256, 0, stream>>>(T2, ln1_g + l * 768, ln1_b + l * 768, Hh, Hl, 6304);
        gemm3_kernel<128, false, false, false><<<dim3(18, 50), 256, 0, stream>>>(
            Hh, Hl, sQKVh, sQKVl, qkv_b + l * 2304, nullptr, QKV, nullptr, nullptr, 6304, 2304, 768);
        attn_kernel<<<768, 256, 0, stream>>>(QKV, Oh, Ol, 197);
        gemm3_kernel<64, false, true, false><<<dim3(12, 50), 256, 0, stream>>>(
            Oh, Ol, sPRJh, sPRJl, proj_b + l * 768, T2, OUT, nullptr, nullptr, 6304, 768, 768);
        ln_kernel<<<6304 / 4, 256, 0, stream>>>(OUT, ln2_g + l * 768, ln2_b + l * 768, Hh, Hl, 6304);
        gemm3_kernel<128, true, false, true><<<dim3(24, 50), 256, 0, stream>>>(
            Hh, Hl, sFC1h, sFC1l, fc1_b + l * 3072, nullptr, nullptr, Mh, Ml, 6304, 3072, 768);
        gemm3_kernel<64, false, true, false><<<dim3(12, 50), 256, 0, stream>>>(
            Mh, Ml, sFC2h, sFC2l, fc2_b + l * 768, OUT, OUT, nullptr, nullptr, 6304, 768, 3072);
        select_kernel<<<(32 * 197 * 768 + 255) / 256, 256, 0, stream>>>(T2, OUT, act, i);
    }

    // --- final LN + head
    head_kernel<<<32, 128, 0, stream>>>(T2, norm_g, norm_b, head_w, head_b, out);
}